// Round 4
// baseline (222.566 us; speedup 1.0000x reference)
//
#include <hip/hip_runtime.h>

#define ALPHA 0.2f
#define BB 4
#define NN 2048
#define IC 256
#define OC 32

// ---------------------------------------------------------------------------
// Kernel 1: h = features @ W  ([B,N,IC] x [IC,OC] -> [B,N,OC])
//           f1 = h @ a[:OC],  f2 = h @ a[OC:]   (per-row scalars)
// One block (64 threads) per row (b*N+n). Lanes 0..31 each own one c.
// ---------------------------------------------------------------------------
__global__ void k1_hproj(const float* __restrict__ feat,
                         const float* __restrict__ W,
                         const float* __restrict__ a,
                         float* __restrict__ h,
                         float* __restrict__ f1,
                         float* __restrict__ f2) {
    __shared__ float s_feat[IC];
    int row = blockIdx.x;           // b*N + n
    int tid = threadIdx.x;          // 0..63
    // cooperative load of the 256-float feature row (64 lanes x float4)
    ((float4*)s_feat)[tid] = ((const float4*)(feat + (size_t)row * IC))[tid];
    __syncthreads();
    if (tid < OC) {
        int c = tid;
        float acc = 0.f;
        #pragma unroll 8
        for (int k = 0; k < IC; ++k)
            acc += s_feat[k] * W[k * OC + c];
        h[(size_t)row * OC + c] = acc;
        float v1 = acc * a[c];
        float v2 = acc * a[OC + c];
        #pragma unroll
        for (int m = 16; m >= 1; m >>= 1) {
            v1 += __shfl_xor(v1, m, 64);
            v2 += __shfl_xor(v2, m, 64);
        }
        if (c == 0) { f1[row] = v1; f2[row] = v2; }
    }
}

// ---------------------------------------------------------------------------
// Kernel 2: cij[i,j] = sum_c distance[i,j,c] * We[c]   (512 MB stream)
// 8 lanes per output element, float4 loads -> fully coalesced 1KB/wave-instr.
// ---------------------------------------------------------------------------
__global__ void k2_cij(const float* __restrict__ distance,
                       const float* __restrict__ We,
                       float* __restrict__ cij) {
    int tid = threadIdx.x;
    int r = tid & 7;                         // lane within group of 8
    float4 w = ((const float4*)We)[r];
    const size_t elems_per_block = 256 / 8;  // 32
    size_t elem = (size_t)blockIdx.x * elems_per_block + (tid >> 3);
    size_t stride = (size_t)gridDim.x * elems_per_block;
    const size_t total = (size_t)NN * NN;
    const float4* d4 = (const float4*)distance;
    for (; elem < total; elem += stride) {
        float4 d = d4[elem * 8 + r];
        float v = d.x * w.x + d.y * w.y + d.z * w.z + d.w * w.w;
        v += __shfl_xor(v, 1, 64);
        v += __shfl_xor(v, 2, 64);
        v += __shfl_xor(v, 4, 64);
        if (r == 0) cij[elem] = v;
    }
}

// ---------------------------------------------------------------------------
// Kernel 3: fused masked-score + softmax + PV, one block per (b,i) row.
//   s_j = mask ? leakyrelu(f1_i + f2_j) + cij_ij : -1e30
//   p_j = exp(s_j - max); out[b,i,c] = sum_j p_j h[b,j,c] / sum_j p_j
// ---------------------------------------------------------------------------
__global__ void k3_attn(const float* __restrict__ f1,
                        const float* __restrict__ f2,
                        const float* __restrict__ h,
                        const float* __restrict__ cij,
                        const int* __restrict__ adj,
                        float* __restrict__ out) {
    __shared__ float s_att[NN];   // 8 KB
    __shared__ float s_red[256];  // 1 KB
    int bi = blockIdx.x;          // b*N + i
    int b = bi >> 11;             // / N
    int i = bi & (NN - 1);
    int tid = threadIdx.x;        // 0..255

    float f1i = f1[bi];
    const float* f2b    = f2 + (size_t)b * NN;
    const int*   adjrow = adj + (size_t)i * NN;
    const float* cijrow = cij + (size_t)i * NN;

    // --- phase A: scores + per-thread max (each thread owns jt = tid + 256k)
    float lmax = -1e30f;
    #pragma unroll
    for (int k = 0; k < NN / 256; ++k) {
        int jt = tid + k * 256;
        float e = f1i + f2b[jt];
        e = e > 0.f ? e : ALPHA * e;
        bool m = (adjrow[jt] > 0) || (jt == i);
        float s = m ? (e + cijrow[jt]) : -1e30f;
        s_att[jt] = s;
        lmax = fmaxf(lmax, s);
    }
    // block max: wave butterfly then cross-wave via LDS
    #pragma unroll
    for (int m = 32; m >= 1; m >>= 1) lmax = fmaxf(lmax, __shfl_xor(lmax, m, 64));
    if ((tid & 63) == 0) s_red[tid >> 6] = lmax;
    __syncthreads();
    lmax = fmaxf(fmaxf(s_red[0], s_red[1]), fmaxf(s_red[2], s_red[3]));

    // --- phase B: exp + sum (same jt ownership -> no cross-thread dep on s_att)
    float lsum = 0.f;
    #pragma unroll
    for (int k = 0; k < NN / 256; ++k) {
        int jt = tid + k * 256;
        float p = __expf(s_att[jt] - lmax);
        s_att[jt] = p;
        lsum += p;
    }
    #pragma unroll
    for (int m = 32; m >= 1; m >>= 1) lsum += __shfl_xor(lsum, m, 64);
    __syncthreads();                       // s_red[0..3] reads done above
    if ((tid & 63) == 0) s_red[tid >> 6] = lsum;
    __syncthreads();                       // also publishes s_att p-values
    float denom = s_red[0] + s_red[1] + s_red[2] + s_red[3];

    // --- phase C: PV. c = tid&31, group g = tid>>5 covers j = g + 8k.
    int c = tid & 31;
    int g = tid >> 5;
    const float* hb = h + (size_t)b * NN * OC;
    float acc = 0.f;
    for (int k = 0; k < NN / 8; ++k) {
        int j = g + k * 8;                 // block reads 8 consecutive h rows/iter
        acc += s_att[j] * hb[(size_t)j * OC + c];
    }
    __syncthreads();                       // denom reads done
    s_red[tid] = acc;
    __syncthreads();
    if (tid < OC) {
        float v = 0.f;
        #pragma unroll
        for (int q = 0; q < 8; ++q) v += s_red[c + 32 * q];
        out[(size_t)bi * OC + c] = v / denom;
    }
}

extern "C" void kernel_launch(void* const* d_in, const int* in_sizes, int n_in,
                              void* d_out, int out_size, void* d_ws, size_t ws_size,
                              hipStream_t stream) {
    const float* feat     = (const float*)d_in[0];  // [B,N,IC]
    const float* W        = (const float*)d_in[1];  // [IC,OC]
    const float* a        = (const float*)d_in[2];  // [2*OC,1]
    const float* We       = (const float*)d_in[3];  // [OC,1]
    const float* distance = (const float*)d_in[4];  // [N,N,OC]
    const int*   adj      = (const int*)d_in[5];    // [N,N]
    float* out = (float*)d_out;

    float* ws  = (float*)d_ws;
    float* h   = ws;                       // B*N*OC
    float* f1  = h  + (size_t)BB * NN * OC;
    float* f2  = f1 + (size_t)BB * NN;
    float* cij = f2 + (size_t)BB * NN;     // N*N  (total ~17.9 MB)

    k1_hproj<<<BB * NN, 64, 0, stream>>>(feat, W, a, h, f1, f2);
    k2_cij<<<8192, 256, 0, stream>>>(distance, We, cij);
    k3_attn<<<BB * NN, 256, 0, stream>>>(f1, f2, h, cij, adj, out);
}

// Round 5
// 188.363 us; speedup vs baseline: 1.1816x; 1.1816x over previous
//
#include <hip/hip_runtime.h>

#define ALPHA 0.2f
#define BB 4
#define NN 2048
#define IC 256
#define OC 32
#define K2_BLOCKS 8192
#define K1_BLOCKS (BB * NN / 4)   // 2048 blocks, 4 rows each
#define TI 8                      // i-rows per k3 block (one wave per row)

// ---------------------------------------------------------------------------
// Fused kernel: block range [0,K2_BLOCKS) streams distance -> cij;
//               block range [K2_BLOCKS, +K1_BLOCKS) computes h, f1, f2.
// The k1 work (L2-bound, ~8us) hides under the 512MB HBM stream.
// ---------------------------------------------------------------------------
__global__ void k12_fused(const float* __restrict__ feat,
                          const float* __restrict__ W,
                          const float* __restrict__ a,
                          const float* __restrict__ We,
                          const float* __restrict__ distance,
                          float* __restrict__ h,
                          float* __restrict__ f1,
                          float* __restrict__ f2,
                          float* __restrict__ cij) {
    __shared__ float s_feat[4][IC];   // only used by k1 branch (4 KB)
    int tid = threadIdx.x;            // 0..255
    if (blockIdx.x < K2_BLOCKS) {
        // --- cij[i,j] = sum_c distance[i,j,c]*We[c]; 8 lanes per element
        int r = tid & 7;
        float4 wvec = ((const float4*)We)[r];
        size_t elem = (size_t)blockIdx.x * 32 + (tid >> 3);
        const size_t stride = (size_t)K2_BLOCKS * 32;
        const size_t total = (size_t)NN * NN;
        const float4* d4 = (const float4*)distance;
        for (; elem < total; elem += stride) {
            float4 d = d4[elem * 8 + r];
            float v = d.x * wvec.x + d.y * wvec.y + d.z * wvec.z + d.w * wvec.w;
            v += __shfl_xor(v, 1, 64);
            v += __shfl_xor(v, 2, 64);
            v += __shfl_xor(v, 4, 64);
            if (r == 0) cij[elem] = v;
        }
    } else {
        // --- h = feat@W, f1 = h@a[:OC], f2 = h@a[OC:]; wave per row
        int bk = blockIdx.x - K2_BLOCKS;
        int wv = tid >> 6, lane = tid & 63;
        int row = bk * 4 + wv;                 // b*N + n
        ((float4*)s_feat[wv])[lane] = ((const float4*)(feat + (size_t)row * IC))[lane];
        __syncthreads();
        if (lane < OC) {
            int c = lane;
            float acc = 0.f;
            #pragma unroll 8
            for (int k = 0; k < IC; ++k)
                acc += s_feat[wv][k] * W[k * OC + c];
            h[(size_t)row * OC + c] = acc;
            float v1 = acc * a[c];
            float v2 = acc * a[OC + c];
            #pragma unroll
            for (int m = 16; m >= 1; m >>= 1) {
                v1 += __shfl_xor(v1, m, 64);
                v2 += __shfl_xor(v2, m, 64);
            }
            if (c == 0) { f1[row] = v1; f2[row] = v2; }
        }
    }
}

// ---------------------------------------------------------------------------
// Kernel 3: block = (b, tile of TI=8 i-rows). Wave w owns row i0+w:
// scores+softmax fully in registers (64-lane butterfly), p -> LDS.
// PV phase: 64 j-groups x 8 threads (4 c's each); each h row is loaded
// ONCE per block (float4, coalesced) and reused for all 8 rows.
// PV L2 traffic: 1024 blocks x 256KB = 256MB (was 2GB).
// ---------------------------------------------------------------------------
__global__ void k3_attn(const float* __restrict__ f1,
                        const float* __restrict__ f2,
                        const float* __restrict__ h,
                        const float* __restrict__ cij,
                        const int* __restrict__ adj,
                        float* __restrict__ out) {
    __shared__ float s_p[TI][NN];          // 64 KB
    __shared__ float s_den[TI];
    __shared__ float s_fin[8][8][TI][4];   // 8 KB: [wave][c4][row][ci]
    int bt = blockIdx.x;                   // 0..1023
    int b  = bt >> 8;                      // NN/TI = 256 tiles
    int i0 = (bt & 255) * TI;
    int tid = threadIdx.x;                 // 0..511
    int wv = tid >> 6;
    int lane = tid & 63;

    // --- phase A+B: wave wv handles row i = i0+wv entirely in-registers
    {
        int i  = i0 + wv;
        int bi = b * NN + i;
        float f1i = f1[bi];
        const float* f2b    = f2 + (size_t)b * NN;
        const int*   adjrow = adj + (size_t)i * NN;
        const float* cijrow = cij + (size_t)i * NN;
        float sc[NN / 64];
        float lmax = -1e30f;
        #pragma unroll
        for (int k = 0; k < NN / 64; ++k) {
            int j = lane + 64 * k;
            float e = f1i + f2b[j];
            e = e > 0.f ? e : ALPHA * e;
            float s = ((adjrow[j] > 0) || (j == i)) ? (e + cijrow[j]) : -1e30f;
            sc[k] = s;
            lmax = fmaxf(lmax, s);
        }
        #pragma unroll
        for (int m = 32; m >= 1; m >>= 1) lmax = fmaxf(lmax, __shfl_xor(lmax, m, 64));
        float lsum = 0.f;
        #pragma unroll
        for (int k = 0; k < NN / 64; ++k) {
            float p = __expf(sc[k] - lmax);
            s_p[wv][lane + 64 * k] = p;
            lsum += p;
        }
        #pragma unroll
        for (int m = 32; m >= 1; m >>= 1) lsum += __shfl_xor(lsum, m, 64);
        if (lane == 0) s_den[wv] = lsum;
    }
    __syncthreads();

    // --- phase C: PV. g = j-group (64 groups of 8 threads), c4 = 4-col block.
    const float* hb = h + (size_t)b * NN * OC;
    int g  = tid >> 3;          // 0..63
    int c4 = tid & 7;           // 0..7
    float acc[TI][4];
    #pragma unroll
    for (int r = 0; r < TI; ++r) { acc[r][0] = acc[r][1] = acc[r][2] = acc[r][3] = 0.f; }
    for (int k = 0; k < NN / 64; ++k) {
        int j = g + 64 * k;
        float4 hv = *(const float4*)(hb + (size_t)j * OC + c4 * 4);
        #pragma unroll
        for (int r = 0; r < TI; ++r) {
            float p = s_p[r][j];            // broadcast within 8-thread group
            acc[r][0] += p * hv.x;
            acc[r][1] += p * hv.y;
            acc[r][2] += p * hv.z;
            acc[r][3] += p * hv.w;
        }
    }
    // reduce the 8 j-groups within each wave (lanes sharing lane&7)
    #pragma unroll
    for (int r = 0; r < TI; ++r) {
        #pragma unroll
        for (int q = 0; q < 4; ++q) {
            float v = acc[r][q];
            v += __shfl_xor(v, 8, 64);
            v += __shfl_xor(v, 16, 64);
            v += __shfl_xor(v, 32, 64);
            acc[r][q] = v;
        }
    }
    if ((tid & 56) == 0) {      // lane 0..7 of each wave holds its wave-partial
        #pragma unroll
        for (int r = 0; r < TI; ++r)
            #pragma unroll
            for (int q = 0; q < 4; ++q)
                s_fin[wv][c4][r][q] = acc[r][q];
    }
    __syncthreads();
    if (tid < TI * OC) {        // 256 threads: (row, col)
        int r = tid >> 5, c = tid & 31;
        float v = 0.f;
        #pragma unroll
        for (int wq = 0; wq < 8; ++wq) v += s_fin[wq][c >> 2][r][c & 3];
        out[((size_t)b * NN + i0 + r) * OC + c] = v / s_den[r];
    }
}

extern "C" void kernel_launch(void* const* d_in, const int* in_sizes, int n_in,
                              void* d_out, int out_size, void* d_ws, size_t ws_size,
                              hipStream_t stream) {
    const float* feat     = (const float*)d_in[0];  // [B,N,IC]
    const float* W        = (const float*)d_in[1];  // [IC,OC]
    const float* a        = (const float*)d_in[2];  // [2*OC,1]
    const float* We       = (const float*)d_in[3];  // [OC,1]
    const float* distance = (const float*)d_in[4];  // [N,N,OC]
    const int*   adj      = (const int*)d_in[5];    // [N,N]
    float* out = (float*)d_out;

    float* ws  = (float*)d_ws;
    float* h   = ws;                       // B*N*OC
    float* f1  = h  + (size_t)BB * NN * OC;
    float* f2  = f1 + (size_t)BB * NN;
    float* cij = f2 + (size_t)BB * NN;     // N*N

    k12_fused<<<K2_BLOCKS + K1_BLOCKS, 256, 0, stream>>>(feat, W, a, We, distance,
                                                         h, f1, f2, cij);
    k3_attn<<<BB * NN / TI, 512, 0, stream>>>(f1, f2, h, cij, adj, out);
}